// Round 1
// 457.705 us; speedup vs baseline: 1.0120x; 1.0120x over previous
//
#include <hip/hip_runtime.h>
#include <math.h>

// ---------------------------------------------------------------------------
// BiAttention round 7:
//  - k_prep ib path: [128][128] bf16 LDS tile with 16B-group XOR swizzle
//    (group ^= row>>3). R6's [128][136] pad gave 16-way conflicts on the
//    transpose read (row stride 68 dwords, lanes step 8 rows -> 544 % 32 = 0,
//    all 16 lanes same bank -> 1.66e7 SQ_LDS_BANK_CONFLICT). Swizzle keyed
//    on row>>3 spreads the 16 transpose lanes bijectively over 8 banks.
//    LDS 34816 -> 32768 (5 blocks/CU instead of 4).
//  - k_p2norm removed: P2 stays raw exp; k_av2 scales acc by 1/sum(psum[row])
//    in the epilogue (row-constant scale commutes through the GEMM).
//  - everything else identical to verified R6.
// Fragment scheme (verified R2..R6): A/B frag row = lane&15, k-group
// (lane>>4)*8 contiguous, XOR swizzle (colgroup ^ (row&7));
// C/D: col = lane&15, row = (lane>>4)*4 + r.
// ---------------------------------------------------------------------------

#define SCALE 0.04419417382415922f  // 1/sqrt(512)

typedef __attribute__((ext_vector_type(8))) short short8;
typedef __attribute__((ext_vector_type(4))) float floatx4;

__device__ __forceinline__ unsigned short f2bf(float x) {
  unsigned u = __float_as_uint(x);
  unsigned r = u + 0x7FFFu + ((u >> 16) & 1u);
  return (unsigned short)(r >> 16);
}
__device__ __forceinline__ float bf2f(unsigned short h) {
  return __uint_as_float(((unsigned)h) << 16);
}
__device__ __forceinline__ unsigned pk2(float a, float b) {
  return (unsigned)f2bf(a) | ((unsigned)f2bf(b) << 16);
}

__device__ __forceinline__ float wave_max(float v) {
#pragma unroll
  for (int o = 32; o > 0; o >>= 1) v = fmaxf(v, __shfl_xor(v, o, 64));
  return v;
}
__device__ __forceinline__ float wave_sum(float v) {
#pragma unroll
  for (int o = 32; o > 0; o >>= 1) v += __shfl_xor(v, o, 64);
  return v;
}

#define GLD_LDS16(gptr, lptr)                                             \
  __builtin_amdgcn_global_load_lds(                                       \
      (const __attribute__((address_space(1))) void*)(gptr),              \
      (__attribute__((address_space(3))) void*)(lptr), 16, 0, 0)

// ---------------------------------------------------------------------------
// Merged prep: idx<512 weights; [512,2560) ib 128x128 tiles; [2560,4608) qb.
__global__ __launch_bounds__(256) void k_prep(
    const float* __restrict__ ib, const float* __restrict__ qb,
    const float* __restrict__ lf_w1, const float* __restrict__ if_w1,
    const float* __restrict__ lf_wm, const float* __restrict__ if_wm,
    const float* __restrict__ fh_w, unsigned short* __restrict__ ib_bf,
    unsigned short* __restrict__ ibT, unsigned short* __restrict__ qb_bf,
    unsigned short* __restrict__ qbT, unsigned short* __restrict__ w1t_lf,
    unsigned short* __restrict__ w1t_if, unsigned short* __restrict__ wcat_t,
    unsigned short* __restrict__ fh_wt) {
  __shared__ __align__(16) char smem[128 * 128 * 2];
  const int idx = blockIdx.x, t = threadIdx.x;

  if (idx < 512) {
    // ---- weights: f32 [K,N] -> bf16 [N, koff+K] (stride 65: conflict-free)
    float(*T)[65] = (float(*)[65])smem;
    const float* src;
    unsigned short* dst;
    int N, ds, koff, k0, n0;
    if (idx < 64) {
      src = lf_w1; dst = w1t_lf; N = 512; ds = 512; koff = 0;
      k0 = (idx & 7) * 64; n0 = (idx >> 3) * 64;
    } else if (idx < 128) {
      int l = idx - 64;
      src = if_w1; dst = w1t_if; N = 512; ds = 512; koff = 0;
      k0 = (l & 7) * 64; n0 = (l >> 3) * 64;
    } else if (idx < 256) {
      int l = idx - 128;
      src = lf_wm; dst = wcat_t; N = 1024; ds = 1024; koff = 0;
      k0 = (l & 7) * 64; n0 = (l >> 3) * 64;
    } else if (idx < 384) {
      int l = idx - 256;
      src = if_wm; dst = wcat_t; N = 1024; ds = 1024; koff = 512;
      k0 = (l & 7) * 64; n0 = (l >> 3) * 64;
    } else {
      int l = idx - 384;
      src = fh_w; dst = fh_wt; N = 512; ds = 1024; koff = 0;
      k0 = (l & 15) * 64; n0 = (l >> 4) * 64;
    }
#pragma unroll
    for (int i = 0; i < 16; i++) {
      int e = t + i * 256, r = e >> 6, c = e & 63;
      T[r][c] = src[(size_t)(k0 + r) * N + n0 + c];
    }
    __syncthreads();
#pragma unroll
    for (int i = 0; i < 8; i++) {
      int e = t + i * 256, r = e >> 5, c2 = (e & 31) * 2;
      *(unsigned*)&dst[(size_t)(n0 + r) * ds + koff + k0 + c2] =
          pk2(T[c2][r], T[c2 + 1][r]);
    }
  } else if (idx < 2560) {
    // ---- ib 128tok x 128h tiles, swizzled [128][128] ----
    // Layout: logical (tok, h) stored at Tb[tok*128 + sw(tok,h)] where the
    // 16B column group (h>>3) is XORed with (tok>>3)&15. Transpose-read lanes
    // differ exactly in row>>3 -> bijective over 8 banks (2-way, free).
    int j = idx - 512;
    int b = j >> 3, tok0 = ((j >> 2) & 1) * 128, h0 = (j & 3) * 128;
    unsigned short* Tb = (unsigned short*)smem;  // [128][128] swizzled
    const float* src = ib + ((size_t)b * 256 + tok0) * 512 + h0;
#pragma unroll
    for (int i = 0; i < 16; i++) {
      int e = t + i * 256, tok = e >> 5, h4 = (e & 31) * 4;
      float4 v = *(const float4*)&src[(size_t)tok * 512 + h4];
      uint2 p;
      p.x = pk2(v.x, v.y);
      p.y = pk2(v.z, v.w);
      int col = ((((h4 >> 3) ^ (tok >> 3)) & 15) << 3) | (h4 & 7);
      *(uint2*)&Tb[tok * 128 + col] = p;
    }
    __syncthreads();
    unsigned short* dbf = ib_bf + ((size_t)b * 256 + tok0) * 512 + h0;
#pragma unroll
    for (int i = 0; i < 8; i++) {
      int e = t + i * 256, tok = e >> 4, g = e & 15;
      int sg = (g ^ (tok >> 3)) & 15;
      *(uint4*)&dbf[(size_t)tok * 512 + g * 8] = *(const uint4*)&Tb[tok * 128 + sg * 8];
    }
    unsigned short* dT = ibT + ((size_t)b * 512 + h0) * 256 + tok0;
#pragma unroll
    for (int i = 0; i < 8; i++) {
      int e = t + i * 256, h = e >> 4, tc = (e & 15) * 8;
      int hg = h >> 3, ho = h & 7;
      unsigned x0 = Tb[(tc + 0) * 128 + ((((tc + 0) >> 3) ^ hg & 15) << 3 ^ ((hg ^ ((tc + 0) >> 3)) & 15) << 3) + 0];  // placeholder (unused)
      (void)x0;
      unsigned y[8];
#pragma unroll
      for (int k = 0; k < 8; k++) {
        int r = tc + k;
        y[k] = Tb[r * 128 + (((hg ^ (r >> 3)) & 15) << 3) + ho];
      }
      uint4 v;
      v.x = y[0] | (y[1] << 16);
      v.y = y[2] | (y[3] << 16);
      v.z = y[4] | (y[5] << 16);
      v.w = y[6] | (y[7] << 16);
      *(uint4*)&dT[(size_t)h * 256 + tc] = v;
    }
  } else {
    // ---- qb 64x64 tiles (R5 path, stride 65: conflict-free) ----
    int j = idx - 2560;
    int b = j >> 3, h0 = (j & 7) * 64;
    float(*T)[65] = (float(*)[65])smem;
    const float* src = qb + (size_t)b * 64 * 512;
    unsigned short* dbf = qb_bf + (size_t)b * 64 * 512;
    unsigned short* dT = qbT + (size_t)b * 512 * 64;
#pragma unroll
    for (int i = 0; i < 16; i++) {
      int e = t + i * 256, r = e >> 6, c = e & 63;
      T[r][c] = src[(size_t)r * 512 + h0 + c];
    }
    __syncthreads();
#pragma unroll
    for (int i = 0; i < 8; i++) {
      int e = t + i * 256, r = e >> 5, c2 = (e & 31) * 2;
      *(unsigned*)&dbf[(size_t)r * 512 + h0 + c2] = pk2(T[r][c2], T[r][c2 + 1]);
    }
#pragma unroll
    for (int i = 0; i < 8; i++) {
      int e = t + i * 256, h = e >> 5, r2 = (e & 31) * 2;
      *(unsigned*)&dT[(size_t)(h0 + h) * 64 + r2] = pk2(T[r2][h], T[r2 + 1][h]);
    }
  }
}

// ---------------------------------------------------------------------------
// Fused scores: per (i-chunk, batch). S[64q x 128i] = qb @ ib^T * SCALE.
// Emits P1[b,i,q] normalized bf16 (softmax over q, qmask) and P2[b,q,i] raw
// exp bf16 (imask; unnormalized) + psum[b*64+q][8] per-wave partial row sums.
__global__ __launch_bounds__(256) void k_scores_f(
    const unsigned short* __restrict__ ibf, const unsigned short* __restrict__ qbf,
    const int* __restrict__ imask, const int* __restrict__ qmask,
    unsigned short* __restrict__ P1, unsigned short* __restrict__ P2,
    float* __restrict__ psum) {
  __shared__ unsigned short As[64 * 64];
  __shared__ unsigned short Bs[128 * 64];
  __shared__ __align__(16) unsigned short X[128 * 72];  // E:[64][136] / Pl:[128][72]
  const int b = blockIdx.y, ic = blockIdx.x, i0 = ic * 128;
  const int t = threadIdx.x, w = t >> 6, lane = t & 63, c = lane & 15, qq = lane >> 4;

  floatx4 acc[4][2];
#pragma unroll
  for (int ti = 0; ti < 4; ti++)
#pragma unroll
    for (int tj = 0; tj < 2; tj++) acc[ti][tj] = (floatx4){0.f, 0.f, 0.f, 0.f};

  for (int k0 = 0; k0 < 512; k0 += 64) {
#pragma unroll
    for (int i = 0; i < 2; i++) {
      int s = i * 256 + t, row = s >> 3, src = (s & 7) ^ (row & 7);
      GLD_LDS16(qbf + ((size_t)b * 64 + row) * 512 + k0 + src * 8,
                &As[(i * 256 + w * 64) * 8]);
    }
#pragma unroll
    for (int i = 0; i < 4; i++) {
      int s = i * 256 + t, row = s >> 3, src = (s & 7) ^ (row & 7);
      GLD_LDS16(ibf + ((size_t)b * 256 + i0 + row) * 512 + k0 + src * 8,
                &Bs[(i * 256 + w * 64) * 8]);
    }
    __syncthreads();
#pragma unroll
    for (int kk = 0; kk < 2; kk++) {
      short8 a[4], bb[2];
#pragma unroll
      for (int ti = 0; ti < 4; ti++)
        a[ti] = *(const short8*)&As[(ti * 16 + c) * 64 + ((kk * 4 + qq) ^ (c & 7)) * 8];
#pragma unroll
      for (int tj = 0; tj < 2; tj++)
        bb[tj] = *(const short8*)&Bs[(w * 32 + tj * 16 + c) * 64 + ((kk * 4 + qq) ^ (c & 7)) * 8];
#pragma unroll
      for (int ti = 0; ti < 4; ti++)
#pragma unroll
        for (int tj = 0; tj < 2; tj++)
          acc[ti][tj] = __builtin_amdgcn_mfma_f32_16x16x32_bf16(a[ti], bb[tj], acc[ti][tj], 0, 0, 0);
    }
    __syncthreads();
  }

  const int il0 = w * 32 + c;  // tj=0 local i; tj=1 is il0+16
  int imsk0 = imask[b * 256 + i0 + il0];
  int imsk1 = imask[b * 256 + i0 + il0 + 16];
  int qm[4][4];
#pragma unroll
  for (int ti = 0; ti < 4; ti++)
#pragma unroll
    for (int rr = 0; rr < 4; rr++) qm[ti][rr] = qmask[b * 64 + ti * 16 + qq * 4 + rr];

  // ---- E phase: raw exp (imask) into X[64][136], per-wave row sums ----
#pragma unroll
  for (int ti = 0; ti < 4; ti++)
#pragma unroll
    for (int rr = 0; rr < 4; rr++) {
      int qv = ti * 16 + qq * 4 + rr;
      float e0 = imsk0 ? 0.f : __expf(acc[ti][0][rr] * SCALE);
      float e1 = imsk1 ? 0.f : __expf(acc[ti][1][rr] * SCALE);
      X[qv * 136 + il0] = f2bf(e0);
      X[qv * 136 + il0 + 16] = f2bf(e1);
      float s = e0 + e1;
#pragma unroll
      for (int o = 1; o <= 8; o <<= 1) s += __shfl_xor(s, o, 64);
      if (c == 0) psum[((size_t)(b * 64 + qv)) * 8 + ic * 4 + w] = s;
    }
  __syncthreads();
#pragma unroll
  for (int i = 0; i < 4; i++) {
    int e2 = t + i * 256, qv = e2 >> 4, g = e2 & 15;
    *(uint4*)&P2[((size_t)b * 64 + qv) * 256 + i0 + g * 8] = *(const uint4*)&X[qv * 136 + g * 8];
  }
  __syncthreads();

  // ---- P1 phase: column softmax over q (qmask), normalized, into X[128][72]
#pragma unroll
  for (int tj = 0; tj < 2; tj++) {
    float ev[4][4];
    float s1 = 0.f;
#pragma unroll
    for (int ti = 0; ti < 4; ti++)
#pragma unroll
      for (int rr = 0; rr < 4; rr++) {
        ev[ti][rr] = qm[ti][rr] ? 0.f : __expf(acc[ti][tj][rr] * SCALE);
        s1 += ev[ti][rr];
      }
    s1 += __shfl_xor(s1, 16, 64);
    s1 += __shfl_xor(s1, 32, 64);
    float inv = 1.f / s1;
    int il = il0 + tj * 16;
#pragma unroll
    for (int ti = 0; ti < 4; ti++)
#pragma unroll
      for (int rr = 0; rr < 4; rr++)
        X[il * 72 + ti * 16 + qq * 4 + rr] = f2bf(ev[ti][rr] * inv);
  }
  __syncthreads();
#pragma unroll
  for (int i = 0; i < 4; i++) {
    int e2 = t + i * 256, il = e2 >> 3, g = e2 & 7;
    *(uint4*)&P1[((size_t)b * 256 + i0 + il) * 64 + g * 8] = *(const uint4*)&X[il * 72 + g * 8];
  }
}

// ---------------------------------------------------------------------------
// ifeat[b,256,512] = P1 @ qb ; B from qbT (bf16 [512][64]). K=64 single step.
__global__ __launch_bounds__(256) void k_av1(const unsigned short* __restrict__ P1,
                                             const unsigned short* __restrict__ qbT,
                                             unsigned short* __restrict__ ifeat) {
  __shared__ unsigned short As[128 * 64];
  __shared__ unsigned short Bs[128 * 64];
  const int b = blockIdx.y, m0 = (blockIdx.x >> 2) * 128, n0 = (blockIdx.x & 3) * 128;
  const int t = threadIdx.x, w = t >> 6, lane = t & 63, c = lane & 15, q = lane >> 4;
  const int wm = w >> 1, wn = w & 1;
#pragma unroll
  for (int i = 0; i < 4; i++) {
    int s = i * 256 + t, row = s >> 3, src = (s & 7) ^ (row & 7);
    GLD_LDS16(P1 + ((size_t)b * 256 + m0 + row) * 64 + src * 8, &As[(i * 256 + w * 64) * 8]);
  }
#pragma unroll
  for (int i = 0; i < 4; i++) {
    int s = i * 256 + t, row = s >> 3, src = (s & 7) ^ (row & 7);
    GLD_LDS16(qbT + ((size_t)b * 512 + n0 + row) * 64 + src * 8, &Bs[(i * 256 + w * 64) * 8]);
  }
  __syncthreads();
  floatx4 acc[4][4];
#pragma unroll
  for (int ti = 0; ti < 4; ti++)
#pragma unroll
    for (int tj = 0; tj < 4; tj++) acc[ti][tj] = (floatx4){0.f, 0.f, 0.f, 0.f};
#pragma unroll
  for (int kk = 0; kk < 2; kk++) {
    short8 a[4], bb[4];
#pragma unroll
    for (int ti = 0; ti < 4; ti++)
      a[ti] = *(const short8*)&As[(wm * 64 + ti * 16 + c) * 64 + ((kk * 4 + q) ^ (c & 7)) * 8];
#pragma unroll
    for (int tj = 0; tj < 4; tj++)
      bb[tj] = *(const short8*)&Bs[(wn * 64 + tj * 16 + c) * 64 + ((kk * 4 + q) ^ (c & 7)) * 8];
#pragma unroll
    for (int ti = 0; ti < 4; ti++)
#pragma unroll
      for (int tj = 0; tj < 4; tj++)
        acc[ti][tj] = __builtin_amdgcn_mfma_f32_16x16x32_bf16(a[ti], bb[tj], acc[ti][tj], 0, 0, 0);
  }
#pragma unroll
  for (int ti = 0; ti < 4; ti++)
#pragma unroll
    for (int rr = 0; rr < 4; rr++) {
      int m = m0 + wm * 64 + ti * 16 + q * 4 + rr;
      unsigned short* op = ifeat + ((size_t)b * 256 + m) * 512 + n0 + wn * 64;
#pragma unroll
      for (int tj = 0; tj < 4; tj++) op[tj * 16 + c] = f2bf(acc[ti][tj][rr]);
    }
}

// ---------------------------------------------------------------------------
// lfeat[b,64,512] = (P2 @ ib) * rowscale ; B from ibT (bf16 [512][256]).
// K=256, 4 chunks. Row scale 1/sum(psum[row][0..7]) folded into epilogue
// (replaces the old k_p2norm pass).
__global__ __launch_bounds__(256) void k_av2(const unsigned short* __restrict__ P2,
                                             const unsigned short* __restrict__ ibT,
                                             const float* __restrict__ psum,
                                             unsigned short* __restrict__ lfeat) {
  __shared__ unsigned short As[64 * 64];
  __shared__ unsigned short Bs[128 * 64];
  const int b = blockIdx.y, n0 = blockIdx.x * 128;
  const int t = threadIdx.x, w = t >> 6, lane = t & 63, c = lane & 15, q = lane >> 4;
  const int wm = w >> 1, wn = w & 1;
  floatx4 acc[2][4];
#pragma unroll
  for (int ti = 0; ti < 2; ti++)
#pragma unroll
    for (int tj = 0; tj < 4; tj++) acc[ti][tj] = (floatx4){0.f, 0.f, 0.f, 0.f};

  for (int kc = 0; kc < 256; kc += 64) {
#pragma unroll
    for (int i = 0; i < 2; i++) {
      int s = i * 256 + t, row = s >> 3, src = (s & 7) ^ (row & 7);
      GLD_LDS16(P2 + ((size_t)b * 64 + row) * 256 + kc + src * 8, &As[(i * 256 + w * 64) * 8]);
    }
#pragma unroll
    for (int i = 0; i < 4; i++) {
      int s = i * 256 + t, row = s >> 3, src = (s & 7) ^ (row & 7);
      GLD_LDS16(ibT + ((size_t)b * 512 + n0 + row) * 256 + kc + src * 8,
                &Bs[(i * 256 + w * 64) * 8]);
    }
    __syncthreads();
#pragma unroll
    for (int kk = 0; kk < 2; kk++) {
      short8 a[2], bb[4];
#pragma unroll
      for (int ti = 0; ti < 2; ti++)
        a[ti] = *(const short8*)&As[(wm * 32 + ti * 16 + c) * 64 + ((kk * 4 + q) ^ (c & 7)) * 8];
#pragma unroll
      for (int tj = 0; tj < 4; tj++)
        bb[tj] = *(const short8*)&Bs[(wn * 64 + tj * 16 + c) * 64 + ((kk * 4 + q) ^ (c & 7)) * 8];
#pragma unroll
      for (int ti = 0; ti < 2; ti++)
#pragma unroll
        for (int tj = 0; tj < 4; tj++)
          acc[ti][tj] = __builtin_amdgcn_mfma_f32_16x16x32_bf16(a[ti], bb[tj], acc[ti][tj], 0, 0, 0);
    }
    __syncthreads();
  }
#pragma unroll
  for (int ti = 0; ti < 2; ti++)
#pragma unroll
    for (int rr = 0; rr < 4; rr++) {
      int m = wm * 32 + ti * 16 + q * 4 + rr;
      const float* ps = psum + ((size_t)(b * 64 + m)) * 8;
      float s = ps[0] + ps[1] + ps[2] + ps[3] + ps[4] + ps[5] + ps[6] + ps[7];
      float inv = 1.f / s;
      unsigned short* op = lfeat + ((size_t)b * 64 + m) * 512 + n0 + wn * 64;
#pragma unroll
      for (int tj = 0; tj < 4; tj++) op[tj * 16 + c] = f2bf(acc[ti][tj][rr] * inv);
    }
}

// ---------------------------------------------------------------------------
// Partial logits: outp[nc*M + m] = sum over n-chunk nc of relu(X@W1+b1)*w2.
__global__ __launch_bounds__(256) void k_logits_part(
    const unsigned short* __restrict__ X, const unsigned short* __restrict__ W1t,
    const float* __restrict__ b1, const float* __restrict__ w2,
    float* __restrict__ outp, int M) {
  __shared__ unsigned short As[128 * 64];
  __shared__ unsigned short Bs[128 * 64];
  __shared__ float red[2][128];
  const int t = threadIdx.x, w = t >> 6, lane = t & 63;
  const int wm = w >> 1, wn = w & 1, c = lane & 15, q = lane >> 4;
  const int idx = blockIdx.x;
  const int m_tile = (idx & 7) + ((idx >> 5) << 3), nc = (idx >> 3) & 3;
  const int m0 = m_tile * 128, n0 = nc * 128;

  floatx4 acc[4][4];
#pragma unroll
  for (int ti = 0; ti < 4; ti++)
#pragma unroll
    for (int tj = 0; tj < 4; tj++) acc[ti][tj] = (floatx4){0.f, 0.f, 0.f, 0.f};

  for (int k0 = 0; k0 < 512; k0 += 64) {
#pragma unroll
    for (int it = 0; it < 4; it++) {
      int s = it * 256 + t, row = s >> 3, src = (s & 7) ^ (row & 7);
      GLD_LDS16(X + (size_t)(m0 + row) * 512 + k0 + src * 8, &As[(it * 256 + w * 64) * 8]);
      GLD_LDS16(W1t + (size_t)(n0 + row) * 512 + k0 + src * 8, &Bs[(it * 256 + w * 64) * 8]);
    }
    __syncthreads();
#pragma unroll
    for (int kk = 0; kk < 2; kk++) {
      short8 a[4], bb[4];
#pragma unroll
      for (int ti = 0; ti < 4; ti++)
        a[ti] = *(const short8*)&As[(wm * 64 + ti * 16 + c) * 64 + ((kk * 4 + q) ^ (c & 7)) * 8];
#pragma unroll
      for (int tj = 0; tj < 4; tj++)
        bb[tj] = *(const short8*)&Bs[(wn * 64 + tj * 16 + c) * 64 + ((kk * 4 + q) ^ (c & 7)) * 8];
#pragma unroll
      for (int ti = 0; ti < 4; ti++)
#pragma unroll
        for (int tj = 0; tj < 4; tj++)
          acc[ti][tj] = __builtin_amdgcn_mfma_f32_16x16x32_bf16(a[ti], bb[tj], acc[ti][tj], 0, 0, 0);
    }
    __syncthreads();
  }
  float partial[4][4] = {};
#pragma unroll
  for (int tj = 0; tj < 4; tj++) {
    int n = n0 + wn * 64 + tj * 16 + c;
    float bia = b1[n], wwv = w2[n];
#pragma unroll
    for (int ti = 0; ti < 4; ti++)
#pragma unroll
      for (int r = 0; r < 4; r++)
        partial[ti][r] += fmaxf(acc[ti][tj][r] + bia, 0.f) * wwv;
  }
#pragma unroll
  for (int msk = 1; msk <= 8; msk <<= 1)
#pragma unroll
    for (int ti = 0; ti < 4; ti++)
#pragma unroll
      for (int r = 0; r < 4; r++)
        partial[ti][r] += __shfl_xor(partial[ti][r], msk, 64);
  if (c == 0) {
#pragma unroll
    for (int ti = 0; ti < 4; ti++)
#pragma unroll
      for (int r = 0; r < 4; r++)
        red[wn][wm * 64 + ti * 16 + q * 4 + r] = partial[ti][r];
  }
  __syncthreads();
  if (t < 128) outp[(size_t)nc * M + m0 + t] = red[0][t] + red[1][t];
}

// ---------------------------------------------------------------------------
__global__ __launch_bounds__(256) void k_attsoft_i(const float* __restrict__ lp,
                                                   const int* __restrict__ imask,
                                                   float* __restrict__ att,
                                                   float* __restrict__ iw_out) {
  __shared__ float red[4];
  const int b = blockIdx.x, t = threadIdx.x;
  const int i = b * 256 + t;
  float x = lp[i] + lp[65536 + i] + lp[131072 + i] + lp[196608 + i];
  float v = imask[i] ? -1e9f : x;
  float wm = wave_max(v);
  if ((t & 63) == 0) red[t >> 6] = wm;
  __syncthreads();
  float mx = fmaxf(fmaxf(red[0], red[1]), fmaxf(red[2], red[3]));
  __syncthreads();
  float e = __expf(v - mx);
  float wsum = wave_sum(e);
  if ((t & 63) == 0) red[t >> 6] = wsum;
  __syncthreads();
  float s = red[0] + red[1] + red[2] + red[3];
  float p = e / s;
  att[i] = p;
  iw_out[i] = p;
}

__global__ __launch_bounds__(64) void k_attsoft_l(const float* __restrict__ lp,
                                                  const int* __restrict__ qmask,
                                                  float* __restrict__ att) {
  const int b = blockIdx.x, t = threadIdx.x;
  const int i = b * 64 + t;
  float x = lp[i] + lp[16384 + i] + lp[32768 + i] + lp[49152 + i];
  float v = qmask[i] ? -1e9f : x;
  float mx = wave_max(v);
  float e = __expf(v - mx);
  float s = wave_sum(e);
  att[i] = e / s;
}

// pooled_bf[b*1024 + ooff + h] = sum_l att[b,l] * X[b,l,h]
__global__ __launch_bounds__(256) void k_pooled(const unsigned short* __restrict__ X,
                                                const float* __restrict__ att, int L,
                                                unsigned short* __restrict__ out,
                                                int ooff) {
  __shared__ float ar[256];
  const int b = blockIdx.x, t = threadIdx.x;
  if (t < L) ar[t] = att[b * L + t];
  __syncthreads();
  float a0 = 0.f, a1 = 0.f;
  const unsigned short* Xb = X + (size_t)b * L * 512 + 2 * t;
  for (int l = 0; l < L; l++) {
    unsigned u = *(const unsigned*)&Xb[(size_t)l * 512];
    float a = ar[l];
    a0 += a * bf2f((unsigned short)(u & 0xffff));
    a1 += a * bf2f((unsigned short)(u >> 16));
  }
  *(unsigned*)&out[(size_t)b * 1024 + ooff + 2 * t] = pk2(a0, a1);
}

// ---------------------------------------------------------------------------
// Epilogue GEMM: out[M,N] = X[M,K]bf16 @ Wt[N,K]bf16 + biasA (+biasB).
__global__ __launch_bounds__(256) void k_egemm(const unsigned short* __restrict__ X,
                                               const unsigned short* __restrict__ Wt,
                                               const float* __restrict__ biasA,
                                               const float* __restrict__ biasB,
                                               float* __restrict__ outf,
                                               unsigned short* __restrict__ outbf,
                                               int N, int K) {
  __shared__ unsigned short As[64 * 64];
  __shared__ unsigned short Bs[64 * 64];
  const int n0 = blockIdx.x * 64, m0 = blockIdx.y * 64;
  const int t = threadIdx.x, w = t >> 6, lane = t & 63, c = lane & 15, q = lane >> 4;
  const int wm = w >> 1, wn = w & 1;
  floatx4 acc[2][2];
#pragma unroll
  for (int ti = 0; ti < 2; ti++)
#pragma unroll
    for (int tj = 0; tj < 2; tj++) acc[ti][tj] = (floatx4){0.f, 0.f, 0.f, 0.f};

  for (int k0 = 0; k0 < K; k0 += 64) {
#pragma unroll
    for (int i = 0; i < 2; i++) {
      int s = i * 256 + t, row = s >> 3, src = (s & 7) ^ (row & 7);
      GLD_LDS16(X + (size_t)(m0 + row) * K + k0 + src * 8, &As[(i * 256 + w * 64) * 8]);
      GLD_LDS16(Wt + (size_t)(n0 + row) * K + k0 + src * 8, &Bs[(i * 256 + w * 64) * 8]);
    }
    __syncthreads();
#pragma unroll
    for (int kk = 0; kk < 2; kk++) {
      short8 a[2], bb[2];
#pragma unroll
      for (int ti = 0; ti < 2; ti++)
        a[ti] = *(const short8*)&As[(wm * 32 + ti * 16 + c) * 64 + ((kk * 4 + q) ^ (c & 7)) * 8];
#pragma unroll
      for (int tj = 0; tj < 2; tj++)
        bb[tj] = *(const short8*)&Bs[(wn * 32 + tj * 16 + c) * 64 + ((kk * 4 + q) ^ (c & 7)) * 8];
#pragma unroll
      for (int ti = 0; ti < 2; ti++)
#pragma unroll
        for (int tj = 0; tj < 2; tj++)
          acc[ti][tj] = __builtin_amdgcn_mfma_f32_16x16x32_bf16(a[ti], bb[tj], acc[ti][tj], 0, 0, 0);
    }
    __syncthreads();
  }
#pragma unroll
  for (int tj = 0; tj < 2; tj++) {
    int n = n0 + wn * 32 + tj * 16 + c;
    float bias = biasA[n] + (biasB ? biasB[n] : 0.f);
#pragma unroll
    for (int ti = 0; ti < 2; ti++)
#pragma unroll
      for (int rr = 0; rr < 4; rr++) {
        int m = m0 + wm * 32 + ti * 16 + q * 4 + rr;
        float v = acc[ti][tj][rr] + bias;
        if (outbf) outbf[(size_t)m * N + n] = f2bf(v);
        else outf[(size_t)m * N + n] = v;
      }
  }
}

// ---------------------------------------------------------------------------
extern "C" void kernel_launch(void* const* d_in, const int* in_sizes, int n_in,
                              void* d_out, int out_size, void* d_ws, size_t ws_size,
                              hipStream_t stream) {
  const float* ib = (const float*)d_in[0];
  const float* qb = (const float*)d_in[1];
  const int* imask = (const int*)d_in[2];
  const int* qmask = (const int*)d_in[3];
  const float* lf_w1 = (const float*)d_in[4];
  const float* lf_b1 = (const float*)d_in[5];
  const float* lf_w2 = (const float*)d_in[6];
  const float* lf_wm = (const float*)d_in[8];
  const float* lf_bm = (const float*)d_in[9];
  const float* if_w1 = (const float*)d_in[10];
  const float* if_b1 = (const float*)d_in[11];
  const float* if_w2 = (const float*)d_in[12];
  const float* if_wm = (const float*)d_in[14];
  const float* if_bm = (const float*)d_in[15];
  const float* fh_w = (const float*)d_in[16];
  const float* fh_b = (const float*)d_in[17];
  float* out = (float*)d_out;  // [256*512] out, then [256*256] i_weight

  float* lp_i = (float*)d_ws;              // 262,144 (4 x 65536)
  float* lp_l = lp_i + 262144;             // 65,536 (4 x 16384)
  float* att_i = lp_l + 65536;             // 65,536
  float* att_l = att_i + 65536;            // 16,384
  float* psum = att_l + 16384;             // 131,072 (16384 x 8)
  unsigned short* P1 = (unsigned short*)(psum + 131072);  // 4,194,304
  unsigned short* P2 = P1 + 4194304;                      // 4,194,304
  unsigned short* ib_bf = P2 + 4194304;                   // 33,554,432 (ifeat alias)
  unsigned short* qb_bf = ib_bf + 33554432;               // 8,388,608 (lfeat alias)
  unsigned short* qbT = qb_bf + 8388608;                  // 8,388,608
  unsigned short* ibT = qbT + 8388608;                    // 33,554,432
  unsigned short* w1t_lf = ibT + 33554432;                // 262,144
  unsigned short* w1t_if = w1t_lf + 262144;               // 262,144
  unsigned short* wcat_t = w1t_if + 262144;               // 1,048,576
  unsigned short* fh_wt = wcat_t + 1048576;               // 524,288
  unsigned short* pooled_bf = fh_wt + 524288;             // 262,144
  unsigned short* F_bf = pooled_bf + 262144;              // 262,144
  unsigned short* ifeat = ib_bf;  // ib_bf dead after k_scores_f
  unsigned short* lfeat = qb_bf;  // qb_bf dead after k_scores_f

  k_prep<<<4608, 256, 0, stream>>>(ib, qb, lf_w1, if_w1, lf_wm, if_wm, fh_w,
                                   ib_bf, ibT, qb_bf, qbT, w1t_lf, w1t_if,
                                   wcat_t, fh_wt);

  k_scores_f<<<dim3(2, 256), 256, 0, stream>>>(ib_bf, qb_bf, imask, qmask, P1, P2, psum);
  k_av1<<<dim3(8, 256), 256, 0, stream>>>(P1, qbT, ifeat);
  k_av2<<<dim3(4, 256), 256, 0, stream>>>(P2, ibT, psum, lfeat);

  k_logits_part<<<2048, 256, 0, stream>>>(ifeat, w1t_lf, lf_b1, lf_w2, lp_i, 65536);
  k_logits_part<<<512, 256, 0, stream>>>(lfeat, w1t_if, if_b1, if_w2, lp_l, 16384);
  k_attsoft_i<<<256, 256, 0, stream>>>(lp_i, imask, att_i, out + 131072);
  k_attsoft_l<<<256, 64, 0, stream>>>(lp_l, qmask, att_l);
  k_pooled<<<256, 256, 0, stream>>>(ifeat, att_i, 256, pooled_bf, 0);
  k_pooled<<<256, 256, 0, stream>>>(lfeat, att_l, 64, pooled_bf, 512);

  k_egemm<<<dim3(16, 4), 256, 0, stream>>>(pooled_bf, wcat_t, lf_bm, if_bm,
                                           nullptr, F_bf, 1024, 1024);
  k_egemm<<<dim3(8, 4), 256, 0, stream>>>(F_bf, fh_wt, fh_b, nullptr,
                                          out, nullptr, 512, 1024);
}